// Round 11
// baseline (226.070 us; speedup 1.0000x reference)
//
#include <hip/hip_runtime.h>
#include <hip/hip_bf16.h>

// Problem shapes (fixed):
//   hidden_states fp32 [WORLD=8][SEQ=2048][HID=4096]
//   gate_proj     fp32 [OUTD=8192][HID=4096]
//   out           fp32 [SEQ=2048][OUTD=8192]
// out = (sum_w hs[w]) @ W^T   (reduce-scatter sum commutes into the GEMM)
// W fp32->bf16 is FUSED into the GEMM's B-staging with COALESCED fp32 loads
// (fixes r9's 4x cache-line-amplified scatter): saves the separate convert
// pass's 128MB read + 64MB write, GEMM reads W fp32 directly.

#define HID   4096
#define SEQ   2048
#define WORLD 8
#define OUTD  8192

typedef __bf16 bf16x8 __attribute__((ext_vector_type(8)));
typedef short  s16x8  __attribute__((ext_vector_type(8)));
typedef float  f32x4  __attribute__((ext_vector_type(4)));
typedef int    i32x2  __attribute__((ext_vector_type(2)));

typedef const __attribute__((address_space(1))) void* gas1_ptr;
typedef __attribute__((address_space(3))) void*       las3_ptr;

static __device__ __forceinline__ unsigned short f2bf(float f) {
    union { float f; unsigned u; } v; v.f = f;
    unsigned u = v.u;
    u += 0x7fffu + ((u >> 16) & 1u);   // round-to-nearest-even
    return (unsigned short)(u >> 16);
}

// pack two fp32 -> one u32 of 2 bf16 (round-half-up; passed r9 at absmax 0.125)
static __device__ __forceinline__ unsigned pack_bf2(float a, float b) {
    unsigned ua = __builtin_bit_cast(unsigned, a) + 0x8000u;
    unsigned ub = __builtin_bit_cast(unsigned, b) + 0x8000u;
    return (ua >> 16) | (ub & 0xffff0000u);
}

// ------------- Kernel 1: reduce over world dim + cast to bf16 -------------
__global__ void reduce_x_kernel(const float* __restrict__ hs,
                                unsigned short* __restrict__ xb) {
    const int total4 = SEQ * HID / 4;
    const float4* h4 = (const float4*)hs;
    ushort4* o4 = (ushort4*)xb;
    for (int i = blockIdx.x * blockDim.x + threadIdx.x; i < total4;
         i += gridDim.x * blockDim.x) {
        float4 s = h4[i];
        #pragma unroll
        for (int w = 1; w < WORLD; ++w) {
            float4 t = h4[i + w * total4];
            s.x += t.x; s.y += t.y; s.z += t.z; s.w += t.w;
        }
        ushort4 o;
        o.x = f2bf(s.x); o.y = f2bf(s.y); o.z = f2bf(s.z); o.w = f2bf(s.w);
        o4[i] = o;
    }
}

// ---- Kernel 2: 256x256 bf16 GEMM C = A * W^T with fused W fp32->bf16 staging ----
// 8 waves (2Mx4N), 128x64 out/wave. LDS: A dbuf [2][256][64] via global_load_lds
// (pre-swizzled source); B dbuf [2][256][64] bf16 via reg-stage:
//   LOADB: 8 x f32x4 COALESCED (instr j: rows wave*32+j*4+(lane>>4),
//          cols (lane&15)*4 -> 4 rows x 256B contiguous per instr)
//   WRITE_B: pack_bf2 -> 8 x ds_write_b64 at swizzled slot
//          (16B slot s=(lane&15)>>1, half=lane&1; slot' = s ^ (row&7);
//           row-XOR spreads the 4-row bank aliasing into disjoint quads)
// Per K-tile t (buf p), ONE barrier:
//   BARRIER; WRITE_B(q)<-breg=B(t+1) [loads 1 tile old: zero-stall wait];
//   STG_A4(q,t+1); LOADB(t+2)->breg; 24 ds_reads + 64 MFMA (compiler lgkm);
//   LGKM0 [drains this tile's ds_writes, all ~4500cyc old];
//   VMC8 [certifies 4 A-stages, leaves 8 B-loads in flight]. Never false drain.

#define BM 256
#define BN 256
#define BK 64
#define KSTEPS (HID / BK)   // 64

__global__ __launch_bounds__(512, 2)
void gemm_bt_kernel(const unsigned short* __restrict__ A,
                    const float* __restrict__ W,
                    float* __restrict__ C) {
    __shared__ __align__(16) unsigned short lsA[2][BM * BK];   // 64 KiB
    __shared__ __align__(16) unsigned short lsB[2][BN * BK];   // 64 KiB

    const int tid  = threadIdx.x;
    const int lane = tid & 63;
    const int wave = tid >> 6;
    const int wm   = wave >> 2;     // 0..1  -> rows wm*128
    const int wn   = wave & 3;      // 0..3  -> cols wn*64

    // 2D XCD tiling: xcd = bid&7 -> (gm,gn)=(xcd>>2, xcd&3); local 32 blocks = 4x8.
    const int bid   = blockIdx.x;
    const int xcd   = bid & 7;
    const int local = bid >> 3;               // 0..31
    const int bm = (xcd >> 2) * 4 + (local >> 3);   // 0..7
    const int bn = (xcd & 3) * 8 + (local & 7);     // 0..31

    // ---- A staging geometry: lane -> (subrow = lane>>3, slot = lane&7) ----
    const int subrow = lane >> 3;
    const int slot   = lane & 7;
    const int scol   = (slot ^ subrow) * 8;   // pre-swizzled global col (elems)
    const unsigned short* aBase =
        A + (size_t)(bm * BM + wave * 8 + subrow) * HID + scol;
    const int ldsW = wave * 8 * BK;           // wave-uniform LDS elem offset

#define ST_A(buf, ktv, l) __builtin_amdgcn_global_load_lds(                     \
        (gas1_ptr)(aBase + (size_t)(ktv) * BK + (size_t)(l) * 64 * HID),        \
        (las3_ptr)(&lsA[buf][(l) * 64 * BK + ldsW]), 16, 0, 0)
#define STG_A4(buf, ktv) do { ST_A(buf, ktv, 0); ST_A(buf, ktv, 1);             \
                              ST_A(buf, ktv, 2); ST_A(buf, ktv, 3); } while (0)

    // ---- B reg-staging geometry (COALESCED) ----
    // instr j: row = wave*32 + j*4 + (lane>>4), col = (lane&15)*4 (fp32)
    const int brow0 = wave * 32 + (lane >> 4);       // + j*4
    const float* wBase =
        W + (size_t)(bn * BN + brow0) * HID + (lane & 15) * 4;

#define LOADB(T) do { _Pragma("unroll")                                         \
    for (int j = 0; j < 8; ++j)                                                 \
        breg[j] = *(const f32x4*)(wBase + (size_t)(T) * BK +                    \
                                  (size_t)j * 4 * HID); } while (0)

    // write: 8B granule g = lane&15 -> slot s = g>>1, half = g&1
    const int wslot = (lane & 15) >> 1;
    const int whalf = (lane & 15) & 1;
#define WRITE_B(Q) do { _Pragma("unroll")                                       \
    for (int j = 0; j < 8; ++j) {                                               \
        const int row_l = brow0 + j * 4;                                        \
        i32x2 wv;                                                               \
        wv.x = (int)pack_bf2(breg[j].x, breg[j].y);                             \
        wv.y = (int)pack_bf2(breg[j].z, breg[j].w);                             \
        *(i32x2*)&lsB[Q][row_l * BK + ((wslot ^ (row_l & 7)) * 8) + whalf * 4]  \
            = wv;                                                               \
    } } while (0)

    // ---- fragment geometry ----
    const int fr    = lane & 15;
    const int fq    = lane >> 4;
    const int axor  = fr & 7;                  // (row & 7) for fragment rows
    const int koff0 = ((0 + fq) ^ axor) * 8;   // k-slice s=0
    const int koff1 = ((4 + fq) ^ axor) * 8;   // k-slice s=1
    const int aRowB = (wm * 128 + fr) * BK;
    const int bRowB = (wn * 64 + fr) * BK;

#define RD_A(dst, P, mm, koff) dst = __builtin_bit_cast(bf16x8,                 \
        *(const s16x8*)&lsA[P][aRowB + (mm) * 16 * BK + (koff)])
#define RD_B(dst, P, nn, koff) dst = __builtin_bit_cast(bf16x8,                 \
        *(const s16x8*)&lsB[P][bRowB + (nn) * 16 * BK + (koff)])

#define BARRIER() __builtin_amdgcn_s_barrier()
#define LGKM0()   asm volatile("s_waitcnt lgkmcnt(0)" ::: "memory")
#define VMC8()    asm volatile("s_waitcnt vmcnt(8)" ::: "memory")
#define VMC0()    asm volatile("s_waitcnt vmcnt(0)" ::: "memory")
#define PRIO1()   __builtin_amdgcn_s_setprio(1)
#define PRIO0()   __builtin_amdgcn_s_setprio(0)

// 8-MFMA cluster: m-pair (mb,mb+1) x n0-3, ONE k-slice, vb single-slice array
#define MFMA8(VA, mb)                                                            \
    PRIO1();                                                                     \
    _Pragma("unroll")                                                            \
    for (int m = 0; m < 2; ++m)                                                  \
        _Pragma("unroll")                                                        \
        for (int n = 0; n < 4; ++n)                                              \
            acc[(mb) + m][n] = __builtin_amdgcn_mfma_f32_16x16x32_bf16(          \
                VA[m], vb[n], acc[(mb) + m][n], 0, 0, 0);                        \
    PRIO0()

// One K-tile on buffer P. HAS1: tile T+1 exists; HAS2: tile T+2 exists.
#define TILE(P, T, HAS1, HAS2)                                                   \
    BARRIER();                                                                   \
    if (HAS1) { WRITE_B((P) ^ 1); STG_A4((P) ^ 1, (T) + 1); }                    \
    if (HAS2) { LOADB((T) + 2); }                                                \
    /* ---- k-slice s=0 ---- */                                                  \
    RD_B(vb[0], P, 0, koff0); RD_B(vb[1], P, 1, koff0);                          \
    RD_B(vb[2], P, 2, koff0); RD_B(vb[3], P, 3, koff0);                          \
    RD_A(va[0], P, 0, koff0); RD_A(va[1], P, 1, koff0);                          \
    MFMA8(va, 0);                                                                \
    RD_A(vc[0], P, 2, koff0); RD_A(vc[1], P, 3, koff0);                          \
    MFMA8(vc, 2);                                                                \
    RD_A(va[0], P, 4, koff0); RD_A(va[1], P, 5, koff0);                          \
    MFMA8(va, 4);                                                                \
    RD_A(vc[0], P, 6, koff0); RD_A(vc[1], P, 7, koff0);                          \
    MFMA8(vc, 6);                                                                \
    /* ---- k-slice s=1 ---- */                                                  \
    RD_B(vb[0], P, 0, koff1); RD_B(vb[1], P, 1, koff1);                          \
    RD_B(vb[2], P, 2, koff1); RD_B(vb[3], P, 3, koff1);                          \
    RD_A(va[0], P, 0, koff1); RD_A(va[1], P, 1, koff1);                          \
    MFMA8(va, 0);                                                                \
    RD_A(vc[0], P, 2, koff1); RD_A(vc[1], P, 3, koff1);                          \
    MFMA8(vc, 2);                                                                \
    RD_A(va[0], P, 4, koff1); RD_A(va[1], P, 5, koff1);                          \
    MFMA8(va, 4);                                                                \
    RD_A(vc[0], P, 6, koff1); RD_A(vc[1], P, 7, koff1);                          \
    LGKM0();                    /* drain this tile's ds_writes (~tile-old) */    \
    MFMA8(vc, 6);                                                                \
    if ((HAS1) && (HAS2)) { VMC8(); }      /* certify A-stage; B-loads fly on */ \
    else if (HAS1)        { VMC0(); }      /* tail t=K-2: only 4 stages left */

    f32x4 acc[8][4] = {};
    bf16x8 va[2], vc[2], vb[4];
    f32x4 breg[8];

    // ---- prologue: A(0)->buf0; B(0) load->pack->buf0; B(1)->reg; drain writes ----
    STG_A4(0, 0);
    LOADB(0);
    WRITE_B(0);        // waits B(0) loads (A(0) older -> also retired)
    LOADB(1);          // 8 in flight entering the loop
    LGKM0();           // prologue ds_writes drained before tile0's barrier

    #pragma unroll 1
    for (int t = 0; t < KSTEPS; t += 2) {
        const bool g2 = (t + 2 < KSTEPS);
        const bool g3 = (t + 3 < KSTEPS);
        TILE(0, t,     true, g2);
        TILE(1, t + 1, g2,   g3);
    }

    // ---- epilogue: C/D layout col = lane&15, row = (lane>>4)*4 + j ----
    const long crow0 = (long)bm * BM + wm * 128 + fq * 4;
    const long ccol0 = (long)bn * BN + wn * 64 + fr;
    #pragma unroll
    for (int m = 0; m < 8; ++m)
        #pragma unroll
        for (int n = 0; n < 4; ++n)
            #pragma unroll
            for (int j = 0; j < 4; ++j)
                C[(crow0 + m * 16 + j) * OUTD + ccol0 + n * 16] = acc[m][n][j];
}

extern "C" void kernel_launch(void* const* d_in, const int* in_sizes, int n_in,
                              void* d_out, int out_size, void* d_ws, size_t ws_size,
                              hipStream_t stream) {
    const float* hs = (const float*)d_in[0];
    const float* w  = (const float*)d_in[1];
    float* out = (float*)d_out;

    unsigned short* xb = (unsigned short*)d_ws;      // 16 MB  [SEQ][HID] bf16

    hipLaunchKernelGGL(reduce_x_kernel, dim3(2048), dim3(256), 0, stream, hs, xb);
    hipLaunchKernelGGL(gemm_bt_kernel, dim3((SEQ / BM) * (OUTD / BN)), dim3(512),
                       0, stream, xb, w, out);
}